// Round 11
// baseline (586.593 us; speedup 1.0000x reference)
//
#include <hip/hip_runtime.h>
#include <hip/hip_bf16.h>
#include <stdint.h>

// Problem constants
#define B_   128
#define N_   400
#define F_   128
#define K_   5
#define ROWS (B_ * N_)   // 51200
#define POOLCAP 2048     // per-batch in-edge pool (strict bound: N_*5 = 2000)
#define DCAP 416         // k_delta per-row list view: 6 base + <=399 in-edges
#define MAXFLAG ROWS     // never truncate flag/hedge sets (determinism)
#define GAP_HEDGE 5e-4   // exact 5-6 gap below which the ref fp32 pick may flip
#define DELTA_MAX 0.18f  // hedge only when exact flip impact is below this
#define NW 13            // ceil(400/32) bitmap words per node
#define NCAND 24         // refine candidate set: 4 partners x top-6

typedef __attribute__((ext_vector_type(8))) short bf16x8;
typedef __attribute__((ext_vector_type(4))) float f32x4;

static __device__ __forceinline__ unsigned short f2bf(float f) {
  union { float f; unsigned u; } v; v.f = f;
  unsigned r = v.u + 0x7fff + ((v.u >> 16) & 1);   // RTNE
  return (unsigned short)(r >> 16);
}
static __device__ __forceinline__ float bf2f(unsigned short h) {
  union { unsigned u; float f; } v; v.u = ((unsigned)h) << 16; return v.f;
}

// sorted-ascending (d, j) top-M insertion; ties -> lower index (stable top_k).
template<int M, typename T>
static __device__ __forceinline__ void insM(T d, int j, T bd[], int bj[]) {
  if (d < bd[M - 1] || (d == bd[M - 1] && j < bj[M - 1])) {
    bd[M - 1] = d; bj[M - 1] = j;
#pragma unroll
    for (int q = M - 1; q > 0; --q) {
      bool sw = (bd[q] < bd[q - 1]) || (bd[q] == bd[q - 1] && bj[q] < bj[q - 1]);
      T td = bd[q]; int tj = bj[q];
      if (sw) { bd[q] = bd[q - 1]; bd[q - 1] = td; bj[q] = bj[q - 1]; bj[q - 1] = tj; }
    }
  }
}

// ---------------------------------------------------------------------------
// K0: x -> Y = [hi|lo] bf16 split ([row][256]) + fp32 row norms sq[row].
__global__ __launch_bounds__(256) void k_prep_rows(const float* __restrict__ x,
                                                   unsigned short* __restrict__ Y,
                                                   float* __restrict__ sq) {
  int wave = threadIdx.x >> 6, lane = threadIdx.x & 63;
  int row = blockIdx.x * 4 + wave;
  float2 v = *(const float2*)&x[(size_t)row * F_ + lane * 2];
  unsigned short hx = f2bf(v.x), hy = f2bf(v.y);
  float lx = v.x - bf2f(hx), ly = v.y - bf2f(hy);
  *(unsigned*)&Y[(size_t)row * 256 + lane * 2]       = (unsigned)hx | ((unsigned)hy << 16);
  *(unsigned*)&Y[(size_t)row * 256 + 128 + lane * 2] = (unsigned)f2bf(lx) | ((unsigned)f2bf(ly) << 16);
  float s = v.x * v.x + v.y * v.y;
#pragma unroll
  for (int o = 32; o > 0; o >>= 1) s += __shfl_xor(s, o);
  if (lane == 0) sq[row] = s;
}

// K0b: weights -> bf16 hi/lo, packed [W1l, W1r, W2l, W2r], each 128x128 [n][k]
__global__ __launch_bounds__(256) void k_prep_w(const float* __restrict__ W1l,
                                                const float* __restrict__ W1r,
                                                const float* __restrict__ W2l,
                                                const float* __restrict__ W2r,
                                                unsigned short* __restrict__ Wh,
                                                unsigned short* __restrict__ Wlo) {
  int t = blockIdx.x * 256 + threadIdx.x;  // 0..65535
  int m = t >> 14, e = t & 16383;
  const float* src = (m == 0) ? W1l : (m == 1) ? W1r : (m == 2) ? W2l : W2r;
  float f = src[e];
  unsigned short h = f2bf(f);
  Wh[t] = h;
  Wlo[t] = f2bf(f - bf2f(h));
}

// ---------------------------------------------------------------------------
// K1: per-batch approx 5-NN, dim3(7,B_), per-thread top-6 selection.
#define YJ_STRIDE 264
__global__ __launch_bounds__(256) void k_knn(const unsigned short* __restrict__ Y,
                                             const float* __restrict__ sq,
                                             int* __restrict__ idxout,
                                             int* __restrict__ flagcnt,
                                             int* __restrict__ flagrows,
                                             int* __restrict__ cand) {
  __shared__ unsigned short Yj[64 * YJ_STRIDE];   // 33792 B; reused as merge scratch
  __shared__ float sqj[64];

  int b = blockIdx.y, i0 = blockIdx.x * 64;
  int tid = threadIdx.x, wave = tid >> 6, lane = tid & 63;

  int i_local = wave * 16 + (lane & 15);          // this lane's single output row
  int arow = b * N_ + min(i0 + i_local, N_ - 1);
  float sqi = sq[arow];

  const bf16x8* abase = (const bf16x8*)&Y[(size_t)arow * 256];
  bf16x8 af[8];
#pragma unroll
  for (int kc = 0; kc < 8; ++kc) af[kc] = abase[kc * 4 + (lane >> 4)];

  float bd[6] = {3.4e38f, 3.4e38f, 3.4e38f, 3.4e38f, 3.4e38f, 3.4e38f};
  int   bj[6] = {1 << 30, 1 << 30, 1 << 30, 1 << 30, 1 << 30, 1 << 30};

  const float4* srcb = (const float4*)(Y + (size_t)b * N_ * 256);

  for (int jt = 0; jt < 7; ++jt) {
    int j0 = jt * 64;
    float4* dst4 = (float4*)Yj;
#pragma unroll
    for (int q = 0; q < 8; ++q) {
      int l = tid + 256 * q;
      int r = l >> 5, cc = l & 31;
      int jr = min(j0 + r, N_ - 1);
      dst4[r * 33 + cc] = srcb[jr * 32 + cc];
    }
    if (tid < 64) sqj[tid] = sq[b * N_ + min(j0 + tid, N_ - 1)];
    __syncthreads();

#pragma unroll
    for (int ct = 0; ct < 4; ++ct) {
      f32x4 acc = {0.f, 0.f, 0.f, 0.f};
      int jfr = ct * 16 + (lane & 15);            // A-fragment row (staged j)
      const bf16x8* bbase = (const bf16x8*)&Yj[jfr * YJ_STRIDE];
#pragma unroll
      for (int kc = 0; kc < 12; ++kc) {
        int bidx = (kc & 3) * 4 + ((kc >= 8) ? 16 : 0) + (lane >> 4);
        acc = __builtin_amdgcn_mfma_f32_16x16x32_bf16(bbase[bidx], af[kc & 7], acc, 0, 0, 0);
      }
      int jbase = ct * 16 + (lane >> 4) * 4;      // this lane's 4 output j's
      float4 sjv = *(const float4*)&sqj[jbase];
      float sj4[4] = {sjv.x, sjv.y, sjv.z, sjv.w};
#pragma unroll
      for (int r = 0; r < 4; ++r) {
        int j = j0 + jbase + r;
        float d = sqi + sj4[r] - 2.0f * acc[r];
        if (j < N_) insM<6, float>(d, j, bd, bj);
      }
    }
    __syncthreads();
  }

  // 4 partner lanes per row merge via scratch overlaid on dead Yj (stride 33).
  float* mbd = (float*)Yj;              // 64*33 floats = 8448 B
  int*   mbj = (int*)Yj + 64 * 33;      // next 8448 B
  int slot = i_local * 33 + (lane >> 4) * 6;
#pragma unroll
  for (int q = 0; q < 6; ++q) { mbd[slot + q] = bd[q]; mbj[slot + q] = bj[q]; }
  __syncthreads();

  if (tid < 64) {
    int i = i0 + tid;
    if (i < N_) {
      float fd[6] = {3.4e38f, 3.4e38f, 3.4e38f, 3.4e38f, 3.4e38f, 3.4e38f};
      int   fj[6] = {1 << 30, 1 << 30, 1 << 30, 1 << 30, 1 << 30, 1 << 30};
      for (int q = 0; q < NCAND; ++q)
        insM<6, float>(mbd[tid * 33 + q], mbj[tid * 33 + q], fd, fj);
      int gi = b * N_ + i;
#pragma unroll
      for (int q = 0; q < 5; ++q) idxout[gi * K_ + q] = fj[q];
      if (fd[5] - fd[4] < 0.02f) {
        int pos = atomicAdd(flagcnt, 1);
        if (pos < MAXFLAG) {
          flagrows[pos] = gi;
          for (int q = 0; q < NCAND; ++q) cand[gi * 32 + q] = mbj[tid * 33 + q];
        }
      }
    }
  }
}

// ---------------------------------------------------------------------------
// K1b: exact f64 re-rank of flagged rows (NCAND=24; lanes >=24 pad +inf).
__global__ __launch_bounds__(256) void k_refine(const float* __restrict__ x,
                                                const int* __restrict__ flagrows,
                                                const int* __restrict__ flagcnt,
                                                const int* __restrict__ cand,
                                                int* __restrict__ idx,
                                                int* __restrict__ hcnt,
                                                int* __restrict__ hrows,
                                                int* __restrict__ hab) {
  __shared__ double dbuf[8][32];
  __shared__ int    jbuf[8][32];
  int slot = threadIdx.x >> 5, c = threadIdx.x & 31;
  int nflag = min(*flagcnt, MAXFLAG);
  for (int base = blockIdx.x * 8; base < nflag; base += gridDim.x * 8) {
    int t = base + slot;
    __syncthreads();
    if (t < nflag) {
      if (c < NCAND) {
        int row = flagrows[t];
        int b = row / N_;
        int j = cand[row * 32 + c];
        const float* xi = x + (size_t)row * F_;
        const float* xj = x + (size_t)(b * N_ + j) * F_;
        double s = 0.0;
#pragma unroll
        for (int q = 0; q < 128; ++q) {
          double d = (double)xi[q] - (double)xj[q];
          s = fma(d, d, s);
        }
        dbuf[slot][c] = s; jbuf[slot][c] = j;
      } else {
        dbuf[slot][c] = 1e300; jbuf[slot][c] = 1 << 30;
      }
    }
    __syncthreads();
    if (c == 0 && t < nflag) {
      int row = flagrows[t];
      int b = row / N_;
      double fd[6] = {1e300, 1e300, 1e300, 1e300, 1e300, 1e300};
      int    fj[6] = {1 << 30, 1 << 30, 1 << 30, 1 << 30, 1 << 30, 1 << 30};
      for (int q = 0; q < NCAND; ++q) insM<6, double>(dbuf[slot][q], jbuf[slot][q], fd, fj);
#pragma unroll
      for (int q = 0; q < 5; ++q) idx[row * K_ + q] = fj[q];
      if (fd[5] - fd[4] < GAP_HEDGE) {
        int p = atomicAdd(hcnt, 1);
        if (p < MAXFLAG) {
          hrows[p] = row;
          hab[2 * p]     = b * N_ + fj[4];
          hab[2 * p + 1] = b * N_ + fj[5];
        }
      }
    }
  }
}

// ---------------------------------------------------------------------------
// K2 (bitmap build): deterministic, uncapped, via LDS bit-matrix + atomicOr.
__global__ __launch_bounds__(512) void k_buildg(const int* __restrict__ idx,
                                                const int* __restrict__ c6,
                                                int* __restrict__ L6,
                                                float* __restrict__ W6,
                                                int* __restrict__ pooli,
                                                float* __restrict__ poolw,
                                                int* __restrict__ offi,
                                                int* __restrict__ cnti) {
  __shared__ unsigned bm1[N_][NW];   // weight-1.0 edges: bm1[tgt][src>>5]
  __shared__ unsigned bmh[N_][NW];   // weight-0.5 edges
  __shared__ int cs[512];
  int b = blockIdx.x, t = threadIdx.x;
  int gb0 = b * N_;

  for (int q = t; q < N_ * NW; q += 512) {
    (&bm1[0][0])[q] = 0u;
    (&bmh[0][0])[q] = 0u;
  }

  int i = t;
  int j0 = -1, j1 = -1, j2 = -1, j3 = -1, j4 = -1, y6 = -1;
  if (i < N_) {
    const int* ip = idx + (size_t)(gb0 + i) * 5;
    j0 = ip[0]; j1 = ip[1]; j2 = ip[2]; j3 = ip[3]; j4 = ip[4];
    y6 = c6[gb0 + i];
  }
  __syncthreads();

  if (i < N_) {
    unsigned bit = 1u << (i & 31);
    int w = i >> 5;
    if (j0 != i) atomicOr(&bm1[j0][w], bit);
    if (j1 != i) atomicOr(&bm1[j1][w], bit);
    if (j2 != i) atomicOr(&bm1[j2][w], bit);
    if (j3 != i) atomicOr(&bm1[j3][w], bit);
    if (j4 != i) {
      if (y6 >= 0) atomicOr(&bmh[j4][w], bit); else atomicOr(&bm1[j4][w], bit);
    }
    if (y6 >= 0 && y6 != i) atomicOr(&bmh[y6][w], bit);
  }
  __syncthreads();

  // base slots (w2 from bitmap)
  if (i < N_) {
    int gi = gb0 + i;
    int   jj[6]  = {j0, j1, j2, j3, j4, y6};
    float w1s[6] = {1.f, 1.f, 1.f, 1.f,
                    (y6 >= 0) ? 0.5f : 1.f,
                    (y6 >= 0) ? 0.5f : 0.f};
#pragma unroll
    for (int k = 0; k < 6; ++k) {
      int j = jj[k]; float w1 = w1s[k];
      size_t sl = (size_t)gi * 6 + k;
      if (w1 <= 0.f || j < 0) { L6[sl] = gi; W6[sl] = 0.f; continue; }
      if (j == i)             { L6[sl] = gi; W6[sl] = 1.f; continue; }
      float w2 = ((bm1[i][j >> 5] >> (j & 31)) & 1) ? 1.f
               : (((bmh[i][j >> 5] >> (j & 31)) & 1) ? 0.5f : 0.f);
      L6[sl] = gb0 + j; W6[sl] = fmaxf(w1, w2);
    }
  }

  // masked in-edge words + count (exclude self + own listed neighbors)
  unsigned mw[NW];
  int cnt_i = 0;
  if (i < N_) {
#pragma unroll
    for (int w = 0; w < NW; ++w) {
      unsigned ex = 0;
      if ((i  >> 5) == w) ex |= 1u << (i  & 31);
      if ((j0 >> 5) == w) ex |= 1u << (j0 & 31);
      if ((j1 >> 5) == w) ex |= 1u << (j1 & 31);
      if ((j2 >> 5) == w) ex |= 1u << (j2 & 31);
      if ((j3 >> 5) == w) ex |= 1u << (j3 & 31);
      if ((j4 >> 5) == w) ex |= 1u << (j4 & 31);
      if (y6 >= 0 && (y6 >> 5) == w) ex |= 1u << (y6 & 31);
      unsigned m = (bm1[i][w] | bmh[i][w]) & ~ex;
      mw[w] = m;
      cnt_i += __popc(m);
    }
  } else {
#pragma unroll
    for (int w = 0; w < NW; ++w) mw[w] = 0u;
  }

  cs[t] = (i < N_) ? cnt_i : 0;
  __syncthreads();
  for (int off = 1; off < 512; off <<= 1) {
    int v = (t >= off) ? cs[t - off] : 0;
    __syncthreads();
    cs[t] += v;
    __syncthreads();
  }

  if (i < N_) {
    int o = b * POOLCAP + cs[t] - cnt_i;   // exclusive offset
    offi[gb0 + i] = o;
    cnti[gb0 + i] = cnt_i;
    int c = 0;
#pragma unroll
    for (int w = 0; w < NW; ++w) {
      unsigned m = mw[w];
      unsigned ones = bm1[i][w];
      while (m) {
        int bit = __ffs(m) - 1; m &= m - 1;
        int r = w * 32 + bit;
        pooli[o + c] = gb0 + r;
        poolw[o + c] = ((ones >> bit) & 1) ? 1.f : 0.5f;
        ++c;
      }
    }
  }
}

// ---------------------------------------------------------------------------
// K2c: EXACT flip-impact. R10 profile: 86us at 0.2% VALUBusy — a few serial
// hub items (nn~200-400, since ga/gb are often the batch hub) on a 64-block
// grid. THIS ROUND: (a) grid 64->512 => <=1 item/block for n<=512;
// (b) mU[s]=max|U[s]| precomputed once/item; single-list candidates (the
// overwhelming majority) use lm = w*mU[s] — BIT-EXACT vs the 128-loop
// (|a*b|=|a|*|b|; mult by positive w is monotone => max commutes) — only
// multi-list duplicates keep the full loop.
__global__ __launch_bounds__(128) void k_delta(
    const float* __restrict__ P, const float* __restrict__ Qb,
    const float* __restrict__ b1, const unsigned short* __restrict__ h1b,
    const float* __restrict__ sumP, const float* __restrict__ degv,
    const int* __restrict__ L6, const float* __restrict__ W6,
    const int* __restrict__ pooli, const float* __restrict__ poolw,
    const int* __restrict__ offi, const int* __restrict__ cnti,
    const int* __restrict__ idx,
    const int* __restrict__ hcnt, const int* __restrict__ hrows,
    const int* __restrict__ hab,
    const float* __restrict__ W2l, const float* __restrict__ W2r,
    int* __restrict__ c6, int* __restrict__ dcnt, int* __restrict__ dlist) {
  __shared__ float H[3][2][128];      // h1 at {i,a,b} x {G1,G2}
  __shared__ float dH[3][128];        // H[s][1]-H[s][0]
  __shared__ float U[3][128];         // W2l @ dH[s]
  __shared__ float V1[128], V2[128], red[128];
  __shared__ float mU[3];
  __shared__ int   Ls[3][DCAP];
  __shared__ float Wsh[3][DCAP];
  int f = threadIdx.x;
  int n = min(*hcnt, MAXFLAG);
  for (int t = blockIdx.x; t < n; t += gridDim.x) {
    int gi = hrows[t], ga = hab[2 * t], gb = hab[2 * t + 1];
    int bb = gi / N_, iw = gi - bb * N_;
    bool ma = false, mb = false;
#pragma unroll
    for (int q = 0; q < K_; ++q) {
      ma = ma || (idx[ga * K_ + q] == iw);
      mb = mb || (idx[gb * K_ + q] == iw);
    }
    if (ma && mb) continue;           // graphs identical: flip has zero effect
    int rows3[3] = {gi, ga, gb};
    int nn3[3];
    for (int s3 = 0; s3 < 3; ++s3) {
      int r = rows3[s3];
      int cc = cnti[r], oo = offi[r];
      int nn = 6 + cc; nn3[s3] = nn;
      for (int e = f; e < DCAP; e += 128) {
        int li = -1; float lw = 0.f;
        if (e < 6)      { li = L6[(size_t)r * 6 + e]; lw = W6[(size_t)r * 6 + e]; }
        else if (e < nn){ li = pooli[oo + e - 6];     lw = poolw[oo + e - 6]; }
        Ls[s3][e] = li; Wsh[s3][e] = lw;
      }
    }
    for (int s3 = 0; s3 < 3; ++s3) {
      int r = rows3[s3];
      float s1 = sumP[(size_t)r * 128 + f], d1 = degv[r];
      float ds = 0.f, dd = 0.f;
      if (s3 == 0) {
        if (!ma) { ds -= P[(size_t)ga * 128 + f]; dd -= 1.f; }
        if (!mb) { ds += P[(size_t)gb * 128 + f]; dd += 1.f; }
      } else if (s3 == 1) {
        if (!ma) { ds -= P[(size_t)gi * 128 + f]; dd -= 1.f; }
      } else {
        if (!mb) { ds += P[(size_t)gi * 128 + f]; dd += 1.f; }
      }
      float base = b1[f] + Qb[(size_t)r * 128 + f];
      float h0 = fmaxf(s1 / d1 + base, 0.f);
      float h1v = fmaxf((s1 + ds) / (d1 + dd) + base, 0.f);
      H[s3][0][f] = h0;
      H[s3][1][f] = h1v;
      dH[s3][f] = h1v - h0;
    }
    __syncthreads();
    {
      float u0 = 0.f, u1 = 0.f, u2 = 0.f;
      for (int f2 = 0; f2 < 128; ++f2) {
        float wv = W2l[f * 128 + f2];
        u0 += dH[0][f2] * wv;
        u1 += dH[1][f2] * wv;
        u2 += dH[2][f2] * wv;
      }
      U[0][f] = u0; U[1][f] = u1; U[2][f] = u2;
    }
    __syncthreads();
    // mU[s] = max_ff |U[s][ff]| (scratch: red/V1/V2 — rewritten below anyway)
    red[f] = fabsf(U[0][f]);
    V1[f]  = fabsf(U[1][f]);
    V2[f]  = fabsf(U[2][f]);
    __syncthreads();
    for (int o = 64; o > 0; o >>= 1) {
      if (f < o) {
        red[f] = fmaxf(red[f], red[f + o]);
        V1[f]  = fmaxf(V1[f],  V1[f + o]);
        V2[f]  = fmaxf(V2[f],  V2[f + o]);
      }
      __syncthreads();
    }
    if (f == 0) { mU[0] = red[0]; mU[1] = V1[0]; mU[2] = V2[0]; }
    __syncthreads();
    float dmax = 0.f;
    for (int which = 0; which < 3; ++which) {
      float v1 = 0.f, v2 = 0.f;
      float d1r = degv[rows3[which]], d2r = d1r;
      int nnw = nn3[which];
      for (int e2 = 0; e2 < nnw; ++e2) {
        float w = Wsh[which][e2];
        if (w == 0.f) continue;
        int s = Ls[which][e2];
        float hv1, hv2;
        if (s == gi)      { hv1 = H[0][0][f]; hv2 = H[0][1][f]; }
        else if (s == ga) { hv1 = H[1][0][f]; hv2 = H[1][1][f]; }
        else if (s == gb) { hv1 = H[2][0][f]; hv2 = H[2][1][f]; }
        else {
          float hh = bf2f(h1b[(size_t)s * 256 + f]) + bf2f(h1b[(size_t)s * 256 + 128 + f]);
          hv1 = hh; hv2 = hh;
        }
        bool inG2 = true;
        if (which == 0 && s == ga && !ma) inG2 = false;  // i loses a
        if (which == 1 && s == gi && !ma) inG2 = false;  // a loses i
        v1 += w * hv1;
        if (inG2) v2 += w * hv2; else d2r -= w;
      }
      if (which == 0 && !mb) { v2 += H[2][1][f]; d2r += 1.f; }  // i gains b
      if (which == 2 && !mb) { v2 += H[0][1][f]; d2r += 1.f; }  // b gains i
      V1[f] = v1; V2[f] = v2;
      __syncthreads();
      float a1 = 0.f, a2 = 0.f, ow = 0.f;
      for (int f2 = 0; f2 < 128; ++f2) {
        float wl = W2l[f * 128 + f2];
        a1 += V1[f2] * wl;
        a2 += V2[f2] * wl;
        ow += dH[which][f2] * W2r[f * 128 + f2];
      }
      dmax = fmaxf(dmax, fabsf(a2 / d2r - a1 / d1r + ow));
      __syncthreads();
    }
    for (int li = 0; li < 3; ++li) {
      for (int e = f; e < nn3[li]; e += 128) {
        float w = Wsh[li][e];
        if (w == 0.f) continue;
        int r = Ls[li][e];
        if (r == gi || r == ga || r == gb) continue;
        bool dup = false;
        for (int lj = 0; lj < li && !dup; ++lj)
          for (int e2 = 0; e2 < nn3[lj]; ++e2)
            if (Ls[lj][e2] == r && Wsh[lj][e2] != 0.f) { dup = true; break; }
        if (dup) continue;
        float wi = 0.f, wa = 0.f, wb = 0.f;
        if (li == 0) wi = w; else if (li == 1) wa = w; else wb = w;
        int nz = 1;
        for (int lj = li + 1; lj < 3; ++lj)
          for (int e2 = 0; e2 < nn3[lj]; ++e2)
            if (Ls[lj][e2] == r && Wsh[lj][e2] != 0.f) {
              if (lj == 1) { if (wa == 0.f) ++nz; wa = Wsh[lj][e2]; }
              else         { if (wb == 0.f) ++nz; wb = Wsh[lj][e2]; }
            }
        float lm;
        if (nz == 1) {
          lm = (li == 0) ? wi * mU[0] : (li == 1) ? wa * mU[1] : wb * mU[2];
        } else {
          lm = 0.f;
          for (int ff = 0; ff < 128; ++ff)
            lm = fmaxf(lm, fabsf(wi * U[0][ff] + wa * U[1][ff] + wb * U[2][ff]));
        }
        dmax = fmaxf(dmax, lm / degv[r]);
      }
    }
    red[f] = dmax;
    __syncthreads();
    for (int o = 64; o > 0; o >>= 1) {
      if (f < o) red[f] = fmaxf(red[f], red[f + o]);
      __syncthreads();
    }
    if (f == 0 && red[0] < DELTA_MAX) {
      c6[gi] = gb - bb * N_;
      int p = atomicAdd(dcnt, 3);
      dlist[p] = gi; dlist[p + 1] = ga; dlist[p + 2] = gb;
    }
    __syncthreads();
  }
}

// ---------------------------------------------------------------------------
// K3: dual near-exact GEMM, two-phase W staging (65 KB -> 2 blocks/CU).
#define WSTR 130
__global__ __launch_bounds__(256) void k_gemm(const unsigned short* __restrict__ A,
                                              const unsigned short* __restrict__ Whl,
                                              const unsigned short* __restrict__ Whr,
                                              const unsigned short* __restrict__ Wll,
                                              const unsigned short* __restrict__ Wlr,
                                              float* __restrict__ P, float* __restrict__ Q) {
  __shared__ unsigned short W[2 * 128 * WSTR];  // 65 KiB: [hi(128) | lo(128)]
  int tid = threadIdx.x, wave = tid >> 6, lane = tid & 63;

  size_t row = (size_t)blockIdx.x * 64 + wave * 16 + (lane & 15);
  bf16x8 af[8];
#pragma unroll
  for (int s = 0; s < 2; ++s)
#pragma unroll
    for (int kc = 0; kc < 4; ++kc)
      af[s * 4 + kc] = *(const bf16x8*)&A[row * 256 + s * 128 + kc * 32 + (lane >> 4) * 8];

  size_t orow0 = (size_t)blockIdx.x * 64 + wave * 16 + (lane >> 4) * 4;
#pragma unroll
  for (int w = 0; w < 2; ++w) {
    // stage this phase's hi/lo weight pair (1 row per thread, 256 rows)
    {
      int mat = tid >> 7, nrow = tid & 127;
      const unsigned short* src =
          (mat == 0) ? ((w == 0) ? Whl : Whr) + nrow * 128
                     : ((w == 0) ? Wll : Wlr) + nrow * 128;
      unsigned short* dst = &W[(size_t)tid * WSTR];
      if (w) __syncthreads();         // all waves done reading phase-0 W
#pragma unroll
      for (int p = 0; p < 16; ++p) *(bf16x8*)(dst + p * 8) = *(const bf16x8*)(src + p * 8);
    }
    __syncthreads();

    float* O = w ? Q : P;
#pragma unroll
    for (int ct = 0; ct < 8; ++ct) {
      f32x4 acc = {0.f, 0.f, 0.f, 0.f};
      int n = ct * 16 + (lane & 15);
      const unsigned short* bh = &W[(size_t)n * WSTR];
      const unsigned short* bl = &W[(size_t)(128 + n) * WSTR];
#pragma unroll
      for (int kc = 0; kc < 4; ++kc) {
        bf16x8 fh = *(const bf16x8*)(bh + kc * 32 + (lane >> 4) * 8);
        bf16x8 fl_ = *(const bf16x8*)(bl + kc * 32 + (lane >> 4) * 8);
        acc = __builtin_amdgcn_mfma_f32_16x16x32_bf16(af[kc], fh, acc, 0, 0, 0);
        acc = __builtin_amdgcn_mfma_f32_16x16x32_bf16(af[4 + kc], fh, acc, 0, 0, 0);
        acc = __builtin_amdgcn_mfma_f32_16x16x32_bf16(af[kc], fl_, acc, 0, 0, 0);
      }
#pragma unroll
      for (int r = 0; r < 4; ++r)
        O[(orow0 + r) * 128 + ct * 16 + (lane & 15)] = acc[r];
    }
  }
}

// K3b: dirty-row GEMM — identical arithmetic, rows indirected via dlist.
__global__ __launch_bounds__(256) void k_gemm_d(const unsigned short* __restrict__ A,
                                                const unsigned short* __restrict__ Whl,
                                                const unsigned short* __restrict__ Whr,
                                                const unsigned short* __restrict__ Wll,
                                                const unsigned short* __restrict__ Wlr,
                                                float* __restrict__ P, float* __restrict__ Q,
                                                const int* __restrict__ dcnt,
                                                const int* __restrict__ dlist) {
  int dn = *dcnt;
  if (blockIdx.x * 64 >= dn) return;
  __shared__ unsigned short W[4 * 128 * WSTR];
  int tid = threadIdx.x, wave = tid >> 6, lane = tid & 63;
#pragma unroll
  for (int q = 0; q < 2; ++q) {
    int ridx = tid * 2 + q;
    int mat = ridx >> 7, n = ridx & 127;
    const unsigned short* src =
        ((mat == 0) ? Whl : (mat == 1) ? Whr : (mat == 2) ? Wll : Wlr) + n * 128;
    unsigned short* dst = &W[(size_t)ridx * WSTR];
#pragma unroll
    for (int p = 0; p < 16; ++p) *(bf16x8*)(dst + p * 8) = *(const bf16x8*)(src + p * 8);
  }
  __syncthreads();

  for (int tb = blockIdx.x * 64; tb < dn; tb += gridDim.x * 64) {
    size_t row = (size_t)dlist[min(tb + wave * 16 + (lane & 15), dn - 1)];
    bf16x8 af[8];
#pragma unroll
    for (int s = 0; s < 2; ++s)
#pragma unroll
      for (int kc = 0; kc < 4; ++kc)
        af[s * 4 + kc] = *(const bf16x8*)&A[row * 256 + s * 128 + kc * 32 + (lane >> 4) * 8];

    int lo0 = tb + wave * 16 + (lane >> 4) * 4;
#pragma unroll
    for (int w = 0; w < 2; ++w) {
      float* O = w ? Q : P;
#pragma unroll
      for (int ct = 0; ct < 8; ++ct) {
        f32x4 acc = {0.f, 0.f, 0.f, 0.f};
        int n = ct * 16 + (lane & 15);
        const unsigned short* bh = &W[(size_t)(w * 128 + n) * WSTR];
        const unsigned short* bl = &W[(size_t)((2 + w) * 128 + n) * WSTR];
#pragma unroll
        for (int kc = 0; kc < 4; ++kc) {
          bf16x8 fh = *(const bf16x8*)(bh + kc * 32 + (lane >> 4) * 8);
          bf16x8 fl_ = *(const bf16x8*)(bl + kc * 32 + (lane >> 4) * 8);
          acc = __builtin_amdgcn_mfma_f32_16x16x32_bf16(af[kc], fh, acc, 0, 0, 0);
          acc = __builtin_amdgcn_mfma_f32_16x16x32_bf16(af[4 + kc], fh, acc, 0, 0, 0);
          acc = __builtin_amdgcn_mfma_f32_16x16x32_bf16(af[kc], fl_, acc, 0, 0, 0);
        }
#pragma unroll
        for (int r = 0; r < 4; ++r) {
          size_t orow = (size_t)dlist[min(lo0 + r, dn - 1)];
          O[orow * 128 + ct * 16 + (lane & 15)] = acc[r];
        }
      }
    }
  }
}

// ---------------------------------------------------------------------------
// K4: weighted aggregation over base-6 + CSR in-edges (canonical order).
// XCD-aware block swizzle (T1) for L2 batch-window locality.
__global__ __launch_bounds__(256) void k_aggr(const float* __restrict__ P,
                                              const float* __restrict__ Q,
                                              const int* __restrict__ L6,
                                              const float* __restrict__ W6,
                                              const int* __restrict__ pooli,
                                              const float* __restrict__ poolw,
                                              const int* __restrict__ offi,
                                              const int* __restrict__ cnti,
                                              const float* __restrict__ bias,
                                              float* __restrict__ outf,
                                              unsigned short* __restrict__ outb,
                                              float* __restrict__ sumP,
                                              float* __restrict__ degv,
                                              int relu) {
  int bid = blockIdx.x;
  int chunk = (bid & 7) * (gridDim.x >> 3) + (bid >> 3);   // grid % 8 == 0
  int r = chunk * 8 + (threadIdx.x >> 5);
  int l4 = threadIdx.x & 31;                // features 4*l4 .. 4*l4+3
  int m = cnti[r], o = offi[r];
  float4 acc = {0.f, 0.f, 0.f, 0.f};
  float deg = 0.f;
#pragma unroll
  for (int k = 0; k < 6; ++k) {
    float ww = W6[(size_t)r * 6 + k];
    float4 p4 = *(const float4*)&P[(size_t)L6[(size_t)r * 6 + k] * 128 + l4 * 4];
    acc.x += ww * p4.x; acc.y += ww * p4.y;
    acc.z += ww * p4.z; acc.w += ww * p4.w;
    deg += ww;
  }
  for (int q = 0; q < m; ++q) {
    float ww = poolw[o + q];
    float4 p4 = *(const float4*)&P[(size_t)pooli[o + q] * 128 + l4 * 4];
    acc.x += ww * p4.x; acc.y += ww * p4.y;
    acc.z += ww * p4.z; acc.w += ww * p4.w;
    deg += ww;
  }
  if (sumP) {
    *(float4*)&sumP[(size_t)r * 128 + l4 * 4] = acc;
    if (l4 == 0) degv[r] = deg;
  }
  float4 b4 = *(const float4*)&bias[l4 * 4];
  float4 q4 = *(const float4*)&Q[(size_t)r * 128 + l4 * 4];
  float4 v;
  v.x = acc.x / deg + b4.x + q4.x;
  v.y = acc.y / deg + b4.y + q4.y;
  v.z = acc.z / deg + b4.z + q4.z;
  v.w = acc.w / deg + b4.w + q4.w;
  if (relu) {
    v.x = fmaxf(v.x, 0.f); v.y = fmaxf(v.y, 0.f);
    v.z = fmaxf(v.z, 0.f); v.w = fmaxf(v.w, 0.f);
  }
  if (outf) {
    *(float4*)&outf[(size_t)r * 128 + l4 * 4] = v;
  } else {
    ushort4 hi, lo;
    hi.x = f2bf(v.x); hi.y = f2bf(v.y); hi.z = f2bf(v.z); hi.w = f2bf(v.w);
    lo.x = f2bf(v.x - bf2f(hi.x)); lo.y = f2bf(v.y - bf2f(hi.y));
    lo.z = f2bf(v.z - bf2f(hi.z)); lo.w = f2bf(v.w - bf2f(hi.w));
    *(ushort4*)&outb[(size_t)r * 256 + l4 * 4] = hi;
    *(ushort4*)&outb[(size_t)r * 256 + 128 + l4 * 4] = lo;
  }
}

// K4b: dirty-row h1 recompute (relu=1, bf16 hi/lo out) over hedged lists.
__global__ __launch_bounds__(256) void k_aggr_d(const float* __restrict__ P,
                                                const float* __restrict__ Q,
                                                const int* __restrict__ L6,
                                                const float* __restrict__ W6,
                                                const int* __restrict__ pooli,
                                                const float* __restrict__ poolw,
                                                const int* __restrict__ offi,
                                                const int* __restrict__ cnti,
                                                const float* __restrict__ bias,
                                                unsigned short* __restrict__ outb,
                                                const int* __restrict__ dcnt,
                                                const int* __restrict__ dlist) {
  int dn = *dcnt;
  int l4 = threadIdx.x & 31;
  for (int di = blockIdx.x * 8 + (threadIdx.x >> 5); di < dn; di += gridDim.x * 8) {
    int r = dlist[di];
    int m = cnti[r], o = offi[r];
    float4 acc = {0.f, 0.f, 0.f, 0.f};
    float deg = 0.f;
#pragma unroll
    for (int k = 0; k < 6; ++k) {
      float ww = W6[(size_t)r * 6 + k];
      float4 p4 = *(const float4*)&P[(size_t)L6[(size_t)r * 6 + k] * 128 + l4 * 4];
      acc.x += ww * p4.x; acc.y += ww * p4.y;
      acc.z += ww * p4.z; acc.w += ww * p4.w;
      deg += ww;
    }
    for (int q = 0; q < m; ++q) {
      float ww = poolw[o + q];
      float4 p4 = *(const float4*)&P[(size_t)pooli[o + q] * 128 + l4 * 4];
      acc.x += ww * p4.x; acc.y += ww * p4.y;
      acc.z += ww * p4.z; acc.w += ww * p4.w;
      deg += ww;
    }
    float4 b4 = *(const float4*)&bias[l4 * 4];
    float4 q4 = *(const float4*)&Q[(size_t)r * 128 + l4 * 4];
    float4 v;
    v.x = fmaxf(acc.x / deg + b4.x + q4.x, 0.f);
    v.y = fmaxf(acc.y / deg + b4.y + q4.y, 0.f);
    v.z = fmaxf(acc.z / deg + b4.z + q4.z, 0.f);
    v.w = fmaxf(acc.w / deg + b4.w + q4.w, 0.f);
    ushort4 hi, lo;
    hi.x = f2bf(v.x); hi.y = f2bf(v.y); hi.z = f2bf(v.z); hi.w = f2bf(v.w);
    lo.x = f2bf(v.x - bf2f(hi.x)); lo.y = f2bf(v.y - bf2f(hi.y));
    lo.z = f2bf(v.z - bf2f(hi.z)); lo.w = f2bf(v.w - bf2f(hi.w));
    *(ushort4*)&outb[(size_t)r * 256 + l4 * 4] = hi;
    *(ushort4*)&outb[(size_t)r * 256 + 128 + l4 * 4] = lo;
  }
}

// ---------------------------------------------------------------------------
extern "C" void kernel_launch(void* const* d_in, const int* in_sizes, int n_in,
                              void* d_out, int out_size, void* d_ws, size_t ws_size,
                              hipStream_t stream) {
  const float* x   = (const float*)d_in[0];
  const float* W1l = (const float*)d_in[1];
  const float* b1l = (const float*)d_in[2];
  const float* W1r = (const float*)d_in[3];
  const float* W2l = (const float*)d_in[4];
  const float* b2l = (const float*)d_in[5];
  const float* W2r = (const float*)d_in[6];
  float* out = (float*)d_out;

  // Workspace (~146 MB). P2 aliases Y (dead after layer-1 GEMM);
  // Q2 aliases sumP (dead after k_delta).
  char* w = (char*)d_ws;
  unsigned short* Y    = (unsigned short*)w; w += (size_t)ROWS * 256 * 2;
  float*          sq   = (float*)w;          w += (size_t)ROWS * 4;
  unsigned short* Wh   = (unsigned short*)w; w += (size_t)4 * 16384 * 2;
  unsigned short* Wlo  = (unsigned short*)w; w += (size_t)4 * 16384 * 2;
  int*            idx  = (int*)w;            w += (size_t)ROWS * K_ * 4;
  int*            L6   = (int*)w;            w += (size_t)ROWS * 6 * 4;
  float*          W6   = (float*)w;          w += (size_t)ROWS * 6 * 4;
  int*            pooli= (int*)w;            w += (size_t)B_ * POOLCAP * 4;
  float*          poolw= (float*)w;          w += (size_t)B_ * POOLCAP * 4;
  int*            offi = (int*)w;            w += (size_t)ROWS * 4;
  int*            cnti = (int*)w;            w += (size_t)ROWS * 4;
  int*            flags = (int*)w;           w += 64;   // [0]=flagcnt [1]=hcnt [2]=dcnt
  int*            c6   = (int*)w;            w += (size_t)ROWS * 4;
  int*            dlist= (int*)w;            w += (size_t)3 * MAXFLAG * 4;
  int*            flagrows = (int*)w;        w += (size_t)MAXFLAG * 4;
  int*            hrows = (int*)w;           w += (size_t)MAXFLAG * 4;
  int*            hab  = (int*)w;            w += (size_t)MAXFLAG * 8;
  int*            candb = (int*)w;           w += (size_t)ROWS * 32 * 4;
  float*          P    = (float*)w;          w += (size_t)ROWS * 128 * 4;
  float*          Qb   = (float*)w;          w += (size_t)ROWS * 128 * 4;
  unsigned short* h1b  = (unsigned short*)w; w += (size_t)ROWS * 256 * 2;
  float*          sumP = (float*)w;          w += (size_t)ROWS * 128 * 4;
  float*          degv = (float*)w;          w += (size_t)ROWS * 4;
  float* P2 = (float*)Y;      // layer-2 lin_l output (Y dead after gemm1)
  float* Q2 = sumP;           // layer-2 lin_r output (sumP dead after delta)
  (void)ws_size; (void)in_sizes; (void)n_in; (void)out_size;

  hipMemsetAsync(flags, 0, 64, stream);
  hipMemsetAsync(c6, 0xFF, (size_t)ROWS * 4, stream);          // c6 = -1
  k_prep_rows<<<ROWS / 4, 256, 0, stream>>>(x, Y, sq);
  k_prep_w<<<(4 * 16384) / 256, 256, 0, stream>>>(W1l, W1r, W2l, W2r, Wh, Wlo);
  k_knn<<<dim3(7, B_), 256, 0, stream>>>(Y, sq, idx, &flags[0], flagrows, candb);
  // layer-1 GEMM early: P/Qb are graph-independent, needed by k_delta.
  k_gemm<<<ROWS / 64, 256, 0, stream>>>(Y, Wh, Wh + 16384, Wlo, Wlo + 16384, P, Qb);
  k_refine<<<64, 256, 0, stream>>>(x, flagrows, &flags[0], candb, idx,
                                   &flags[1], hrows, hab);
  // pass 1: unhedged build + aggregation (records sumP/degv/h1 for k_delta)
  k_buildg<<<B_, 512, 0, stream>>>(idx, c6, L6, W6, pooli, poolw, offi, cnti);
  k_aggr<<<ROWS / 8, 256, 0, stream>>>(P, Qb, L6, W6, pooli, poolw, offi, cnti,
                                       b1l, nullptr, h1b, sumP, degv, 1);
  k_delta<<<512, 128, 0, stream>>>(P, Qb, b1l, h1b, sumP, degv, L6, W6, pooli,
                                   poolw, offi, cnti, idx, &flags[1], hrows, hab,
                                   W2l, W2r, c6, &flags[2], dlist);
  // pass 2 (surgical): rebuild lists; full layer-2 GEMM on pass-1 h1 (valid for
  // all non-dirty rows); then fix only dirty rows' h1 and P2/Q2; final aggr.
  k_buildg<<<B_, 512, 0, stream>>>(idx, c6, L6, W6, pooli, poolw, offi, cnti);
  k_gemm<<<ROWS / 64, 256, 0, stream>>>(h1b, Wh + 2 * 16384, Wh + 3 * 16384,
                                        Wlo + 2 * 16384, Wlo + 3 * 16384, P2, Q2);
  k_aggr_d<<<64, 256, 0, stream>>>(P, Qb, L6, W6, pooli, poolw, offi, cnti,
                                   b1l, h1b, &flags[2], dlist);
  k_gemm_d<<<32, 256, 0, stream>>>(h1b, Wh + 2 * 16384, Wh + 3 * 16384,
                                   Wlo + 2 * 16384, Wlo + 3 * 16384, P2, Q2,
                                   &flags[2], dlist);
  k_aggr<<<ROWS / 8, 256, 0, stream>>>(P2, Q2, L6, W6, pooli, poolw, offi, cnti,
                                       b2l, out, nullptr, nullptr, nullptr, 0);
}

// Round 12
// 582.501 us; speedup vs baseline: 1.0070x; 1.0070x over previous
//
#include <hip/hip_runtime.h>
#include <hip/hip_bf16.h>
#include <stdint.h>

// Problem constants
#define B_   128
#define N_   400
#define F_   128
#define K_   5
#define ROWS (B_ * N_)   // 51200
#define POOLCAP 2048     // per-batch in-edge pool (strict bound: N_*5 = 2000)
#define DCAP 416         // k_delta per-row list view: 6 base + <=399 in-edges
#define MAXFLAG ROWS     // never truncate flag/hedge sets (determinism)
#define GAP_HEDGE 5e-4   // exact 5-6 gap below which the ref fp32 pick may flip
#define DELTA_MAX 0.18f  // hedge only when exact flip impact is below this
#define NW 13            // ceil(400/32) bitmap words per node
#define NCAND 12         // refine candidate set: 2 halves x top-6

typedef __attribute__((ext_vector_type(8))) short bf16x8;
typedef __attribute__((ext_vector_type(4))) float f32x4;

static __device__ __forceinline__ unsigned short f2bf(float f) {
  union { float f; unsigned u; } v; v.f = f;
  unsigned r = v.u + 0x7fff + ((v.u >> 16) & 1);   // RTNE
  return (unsigned short)(r >> 16);
}
static __device__ __forceinline__ float bf2f(unsigned short h) {
  union { unsigned u; float f; } v; v.u = ((unsigned)h) << 16; return v.f;
}

// sorted-ascending (d, j) top-M insertion; ties -> lower index (stable top_k).
template<int M, typename T>
static __device__ __forceinline__ void insM(T d, int j, T bd[], int bj[]) {
  if (d < bd[M - 1] || (d == bd[M - 1] && j < bj[M - 1])) {
    bd[M - 1] = d; bj[M - 1] = j;
#pragma unroll
    for (int q = M - 1; q > 0; --q) {
      bool sw = (bd[q] < bd[q - 1]) || (bd[q] == bd[q - 1] && bj[q] < bj[q - 1]);
      T td = bd[q]; int tj = bj[q];
      if (sw) { bd[q] = bd[q - 1]; bd[q - 1] = td; bj[q] = bj[q - 1]; bj[q - 1] = tj; }
    }
  }
}

// ---------------------------------------------------------------------------
// K0: x -> Y = [hi|lo] bf16 split ([row][256]) + fp32 row norms sq[row].
__global__ __launch_bounds__(256) void k_prep_rows(const float* __restrict__ x,
                                                   unsigned short* __restrict__ Y,
                                                   float* __restrict__ sq) {
  int wave = threadIdx.x >> 6, lane = threadIdx.x & 63;
  int row = blockIdx.x * 4 + wave;
  float2 v = *(const float2*)&x[(size_t)row * F_ + lane * 2];
  unsigned short hx = f2bf(v.x), hy = f2bf(v.y);
  float lx = v.x - bf2f(hx), ly = v.y - bf2f(hy);
  *(unsigned*)&Y[(size_t)row * 256 + lane * 2]       = (unsigned)hx | ((unsigned)hy << 16);
  *(unsigned*)&Y[(size_t)row * 256 + 128 + lane * 2] = (unsigned)f2bf(lx) | ((unsigned)f2bf(ly) << 16);
  float s = v.x * v.x + v.y * v.y;
#pragma unroll
  for (int o = 32; o > 0; o >>= 1) s += __shfl_xor(s, o);
  if (lane == 0) sq[row] = s;
}

// K0b: weights -> bf16 hi/lo, packed [W1l, W1r, W2l, W2r], each 128x128 [n][k]
__global__ __launch_bounds__(256) void k_prep_w(const float* __restrict__ W1l,
                                                const float* __restrict__ W1r,
                                                const float* __restrict__ W2l,
                                                const float* __restrict__ W2r,
                                                unsigned short* __restrict__ Wh,
                                                unsigned short* __restrict__ Wlo) {
  int t = blockIdx.x * 256 + threadIdx.x;  // 0..65535
  int m = t >> 14, e = t & 16383;
  const float* src = (m == 0) ? W1l : (m == 1) ? W1r : (m == 2) ? W2l : W2r;
  float f = src[e];
  unsigned short h = f2bf(f);
  Wh[t] = h;
  Wlo[t] = f2bf(f - bf2f(h));
}

// ---------------------------------------------------------------------------
// K1: per-batch approx 5-NN, SPLIT-J: dim3(7, B_, 2); blockIdx.z=half picks
// j-tiles 0-3 / 4-6. Per-block serial depth 7 -> 4 tiles; grid 896 -> 1792
// (~7 blocks/CU). Each half writes its per-row top-6 to halfd/halfj; the
// trivial k_kmerge folds the two to the final top-6 — EXACT: distances are
// bit-identical, merged top-6 == global top-6 (k-way selection over the
// strict (d,j) order), flags test the same fd[4]/fd[5].
#define YJ_STRIDE 264
__global__ __launch_bounds__(256) void k_knn(const unsigned short* __restrict__ Y,
                                             const float* __restrict__ sq,
                                             float* __restrict__ halfd,
                                             int* __restrict__ halfj) {
  __shared__ unsigned short Yj[64 * YJ_STRIDE];   // 33792 B; reused as merge scratch
  __shared__ float sqj[64];

  int b = blockIdx.y, i0 = blockIdx.x * 64, half = blockIdx.z;
  int tid = threadIdx.x, wave = tid >> 6, lane = tid & 63;

  int i_local = wave * 16 + (lane & 15);          // this lane's single output row
  int arow = b * N_ + min(i0 + i_local, N_ - 1);
  float sqi = sq[arow];

  const bf16x8* abase = (const bf16x8*)&Y[(size_t)arow * 256];
  bf16x8 af[8];
#pragma unroll
  for (int kc = 0; kc < 8; ++kc) af[kc] = abase[kc * 4 + (lane >> 4)];

  float bd[6] = {3.4e38f, 3.4e38f, 3.4e38f, 3.4e38f, 3.4e38f, 3.4e38f};
  int   bj[6] = {1 << 30, 1 << 30, 1 << 30, 1 << 30, 1 << 30, 1 << 30};

  const float4* srcb = (const float4*)(Y + (size_t)b * N_ * 256);

  int jt0 = half * 4, jt1 = half ? 7 : 4;
  for (int jt = jt0; jt < jt1; ++jt) {
    int j0 = jt * 64;
    float4* dst4 = (float4*)Yj;
#pragma unroll
    for (int q = 0; q < 8; ++q) {
      int l = tid + 256 * q;
      int r = l >> 5, cc = l & 31;
      int jr = min(j0 + r, N_ - 1);
      dst4[r * 33 + cc] = srcb[jr * 32 + cc];
    }
    if (tid < 64) sqj[tid] = sq[b * N_ + min(j0 + tid, N_ - 1)];
    __syncthreads();

#pragma unroll
    for (int ct = 0; ct < 4; ++ct) {
      f32x4 acc = {0.f, 0.f, 0.f, 0.f};
      int jfr = ct * 16 + (lane & 15);            // A-fragment row (staged j)
      const bf16x8* bbase = (const bf16x8*)&Yj[jfr * YJ_STRIDE];
#pragma unroll
      for (int kc = 0; kc < 12; ++kc) {
        int bidx = (kc & 3) * 4 + ((kc >= 8) ? 16 : 0) + (lane >> 4);
        acc = __builtin_amdgcn_mfma_f32_16x16x32_bf16(bbase[bidx], af[kc & 7], acc, 0, 0, 0);
      }
      int jbase = ct * 16 + (lane >> 4) * 4;      // this lane's 4 output j's
      float4 sjv = *(const float4*)&sqj[jbase];
      float sj4[4] = {sjv.x, sjv.y, sjv.z, sjv.w};
#pragma unroll
      for (int r = 0; r < 4; ++r) {
        int j = j0 + jbase + r;
        float d = sqi + sj4[r] - 2.0f * acc[r];
        if (j < N_) insM<6, float>(d, j, bd, bj);
      }
    }
    __syncthreads();
  }

  // 4 partner lanes per row merge via scratch overlaid on dead Yj (stride 33).
  float* mbd = (float*)Yj;              // 64*33 floats = 8448 B
  int*   mbj = (int*)Yj + 64 * 33;      // next 8448 B
  int slot = i_local * 33 + (lane >> 4) * 6;
#pragma unroll
  for (int q = 0; q < 6; ++q) { mbd[slot + q] = bd[q]; mbj[slot + q] = bj[q]; }
  __syncthreads();

  if (tid < 64) {
    int i = i0 + tid;
    if (i < N_) {
      float fd[6] = {3.4e38f, 3.4e38f, 3.4e38f, 3.4e38f, 3.4e38f, 3.4e38f};
      int   fj[6] = {1 << 30, 1 << 30, 1 << 30, 1 << 30, 1 << 30, 1 << 30};
      for (int q = 0; q < 24; ++q)
        insM<6, float>(mbd[tid * 33 + q], mbj[tid * 33 + q], fd, fj);
      size_t gi = (size_t)(b * N_ + i);
#pragma unroll
      for (int q = 0; q < 6; ++q) {
        halfd[gi * 12 + half * 6 + q] = fd[q];
        halfj[gi * 12 + half * 6 + q] = fj[q];
      }
    }
  }
}

// K1m: fold the two half top-6s into the final top-6 + flags + cand.
__global__ __launch_bounds__(256) void k_kmerge(const float* __restrict__ halfd,
                                                const int* __restrict__ halfj,
                                                int* __restrict__ idxout,
                                                int* __restrict__ flagcnt,
                                                int* __restrict__ flagrows,
                                                int* __restrict__ cand) {
  size_t r = (size_t)blockIdx.x * 256 + threadIdx.x;   // ROWS = 200*256
  float fd[6] = {3.4e38f, 3.4e38f, 3.4e38f, 3.4e38f, 3.4e38f, 3.4e38f};
  int   fj[6] = {1 << 30, 1 << 30, 1 << 30, 1 << 30, 1 << 30, 1 << 30};
#pragma unroll
  for (int q = 0; q < 12; ++q)
    insM<6, float>(halfd[r * 12 + q], halfj[r * 12 + q], fd, fj);
#pragma unroll
  for (int q = 0; q < 5; ++q) idxout[r * K_ + q] = fj[q];
  if (fd[5] - fd[4] < 0.02f) {
    int pos = atomicAdd(flagcnt, 1);
    if (pos < MAXFLAG) {
      flagrows[pos] = (int)r;
      for (int q = 0; q < 12; ++q) cand[r * 32 + q] = halfj[r * 12 + q];
    }
  }
}

// ---------------------------------------------------------------------------
// K1b: exact f64 re-rank of flagged rows (NCAND=12; lanes >=12 pad +inf).
__global__ __launch_bounds__(256) void k_refine(const float* __restrict__ x,
                                                const int* __restrict__ flagrows,
                                                const int* __restrict__ flagcnt,
                                                const int* __restrict__ cand,
                                                int* __restrict__ idx,
                                                int* __restrict__ hcnt,
                                                int* __restrict__ hrows,
                                                int* __restrict__ hab) {
  __shared__ double dbuf[8][32];
  __shared__ int    jbuf[8][32];
  int slot = threadIdx.x >> 5, c = threadIdx.x & 31;
  int nflag = min(*flagcnt, MAXFLAG);
  for (int base = blockIdx.x * 8; base < nflag; base += gridDim.x * 8) {
    int t = base + slot;
    __syncthreads();
    if (t < nflag) {
      if (c < NCAND) {
        int row = flagrows[t];
        int b = row / N_;
        int j = cand[(size_t)row * 32 + c];
        const float* xi = x + (size_t)row * F_;
        const float* xj = x + (size_t)(b * N_ + j) * F_;
        double s = 0.0;
#pragma unroll
        for (int q = 0; q < 128; ++q) {
          double d = (double)xi[q] - (double)xj[q];
          s = fma(d, d, s);
        }
        dbuf[slot][c] = s; jbuf[slot][c] = j;
      } else {
        dbuf[slot][c] = 1e300; jbuf[slot][c] = 1 << 30;
      }
    }
    __syncthreads();
    if (c == 0 && t < nflag) {
      int row = flagrows[t];
      int b = row / N_;
      double fd[6] = {1e300, 1e300, 1e300, 1e300, 1e300, 1e300};
      int    fj[6] = {1 << 30, 1 << 30, 1 << 30, 1 << 30, 1 << 30, 1 << 30};
      for (int q = 0; q < NCAND; ++q) insM<6, double>(dbuf[slot][q], jbuf[slot][q], fd, fj);
#pragma unroll
      for (int q = 0; q < 5; ++q) idx[row * K_ + q] = fj[q];
      if (fd[5] - fd[4] < GAP_HEDGE) {
        int p = atomicAdd(hcnt, 1);
        if (p < MAXFLAG) {
          hrows[p] = row;
          hab[2 * p]     = b * N_ + fj[4];
          hab[2 * p + 1] = b * N_ + fj[5];
        }
      }
    }
  }
}

// ---------------------------------------------------------------------------
// K2 (bitmap build): deterministic, uncapped, via LDS bit-matrix + atomicOr.
__global__ __launch_bounds__(512) void k_buildg(const int* __restrict__ idx,
                                                const int* __restrict__ c6,
                                                int* __restrict__ L6,
                                                float* __restrict__ W6,
                                                int* __restrict__ pooli,
                                                float* __restrict__ poolw,
                                                int* __restrict__ offi,
                                                int* __restrict__ cnti) {
  __shared__ unsigned bm1[N_][NW];   // weight-1.0 edges: bm1[tgt][src>>5]
  __shared__ unsigned bmh[N_][NW];   // weight-0.5 edges
  __shared__ int cs[512];
  int b = blockIdx.x, t = threadIdx.x;
  int gb0 = b * N_;

  for (int q = t; q < N_ * NW; q += 512) {
    (&bm1[0][0])[q] = 0u;
    (&bmh[0][0])[q] = 0u;
  }

  int i = t;
  int j0 = -1, j1 = -1, j2 = -1, j3 = -1, j4 = -1, y6 = -1;
  if (i < N_) {
    const int* ip = idx + (size_t)(gb0 + i) * 5;
    j0 = ip[0]; j1 = ip[1]; j2 = ip[2]; j3 = ip[3]; j4 = ip[4];
    y6 = c6[gb0 + i];
  }
  __syncthreads();

  if (i < N_) {
    unsigned bit = 1u << (i & 31);
    int w = i >> 5;
    if (j0 != i) atomicOr(&bm1[j0][w], bit);
    if (j1 != i) atomicOr(&bm1[j1][w], bit);
    if (j2 != i) atomicOr(&bm1[j2][w], bit);
    if (j3 != i) atomicOr(&bm1[j3][w], bit);
    if (j4 != i) {
      if (y6 >= 0) atomicOr(&bmh[j4][w], bit); else atomicOr(&bm1[j4][w], bit);
    }
    if (y6 >= 0 && y6 != i) atomicOr(&bmh[y6][w], bit);
  }
  __syncthreads();

  // base slots (w2 from bitmap)
  if (i < N_) {
    int gi = gb0 + i;
    int   jj[6]  = {j0, j1, j2, j3, j4, y6};
    float w1s[6] = {1.f, 1.f, 1.f, 1.f,
                    (y6 >= 0) ? 0.5f : 1.f,
                    (y6 >= 0) ? 0.5f : 0.f};
#pragma unroll
    for (int k = 0; k < 6; ++k) {
      int j = jj[k]; float w1 = w1s[k];
      size_t sl = (size_t)gi * 6 + k;
      if (w1 <= 0.f || j < 0) { L6[sl] = gi; W6[sl] = 0.f; continue; }
      if (j == i)             { L6[sl] = gi; W6[sl] = 1.f; continue; }
      float w2 = ((bm1[i][j >> 5] >> (j & 31)) & 1) ? 1.f
               : (((bmh[i][j >> 5] >> (j & 31)) & 1) ? 0.5f : 0.f);
      L6[sl] = gb0 + j; W6[sl] = fmaxf(w1, w2);
    }
  }

  // masked in-edge words + count (exclude self + own listed neighbors)
  unsigned mw[NW];
  int cnt_i = 0;
  if (i < N_) {
#pragma unroll
    for (int w = 0; w < NW; ++w) {
      unsigned ex = 0;
      if ((i  >> 5) == w) ex |= 1u << (i  & 31);
      if ((j0 >> 5) == w) ex |= 1u << (j0 & 31);
      if ((j1 >> 5) == w) ex |= 1u << (j1 & 31);
      if ((j2 >> 5) == w) ex |= 1u << (j2 & 31);
      if ((j3 >> 5) == w) ex |= 1u << (j3 & 31);
      if ((j4 >> 5) == w) ex |= 1u << (j4 & 31);
      if (y6 >= 0 && (y6 >> 5) == w) ex |= 1u << (y6 & 31);
      unsigned m = (bm1[i][w] | bmh[i][w]) & ~ex;
      mw[w] = m;
      cnt_i += __popc(m);
    }
  } else {
#pragma unroll
    for (int w = 0; w < NW; ++w) mw[w] = 0u;
  }

  cs[t] = (i < N_) ? cnt_i : 0;
  __syncthreads();
  for (int off = 1; off < 512; off <<= 1) {
    int v = (t >= off) ? cs[t - off] : 0;
    __syncthreads();
    cs[t] += v;
    __syncthreads();
  }

  if (i < N_) {
    int o = b * POOLCAP + cs[t] - cnt_i;   // exclusive offset
    offi[gb0 + i] = o;
    cnti[gb0 + i] = cnt_i;
    int c = 0;
#pragma unroll
    for (int w = 0; w < NW; ++w) {
      unsigned m = mw[w];
      unsigned ones = bm1[i][w];
      while (m) {
        int bit = __ffs(m) - 1; m &= m - 1;
        int r = w * 32 + bit;
        pooli[o + c] = gb0 + r;
        poolw[o + c] = ((ones >> bit) & 1) ? 1.f : 0.5f;
        ++c;
      }
    }
  }
}

// ---------------------------------------------------------------------------
// K2c: EXACT flip-impact (512 blocks; mU fast path for single-list cands).
__global__ __launch_bounds__(128) void k_delta(
    const float* __restrict__ P, const float* __restrict__ Qb,
    const float* __restrict__ b1, const unsigned short* __restrict__ h1b,
    const float* __restrict__ sumP, const float* __restrict__ degv,
    const int* __restrict__ L6, const float* __restrict__ W6,
    const int* __restrict__ pooli, const float* __restrict__ poolw,
    const int* __restrict__ offi, const int* __restrict__ cnti,
    const int* __restrict__ idx,
    const int* __restrict__ hcnt, const int* __restrict__ hrows,
    const int* __restrict__ hab,
    const float* __restrict__ W2l, const float* __restrict__ W2r,
    int* __restrict__ c6, int* __restrict__ dcnt, int* __restrict__ dlist) {
  __shared__ float H[3][2][128];      // h1 at {i,a,b} x {G1,G2}
  __shared__ float dH[3][128];        // H[s][1]-H[s][0]
  __shared__ float U[3][128];         // W2l @ dH[s]
  __shared__ float V1[128], V2[128], red[128];
  __shared__ float mU[3];
  __shared__ int   Ls[3][DCAP];
  __shared__ float Wsh[3][DCAP];
  int f = threadIdx.x;
  int n = min(*hcnt, MAXFLAG);
  for (int t = blockIdx.x; t < n; t += gridDim.x) {
    int gi = hrows[t], ga = hab[2 * t], gb = hab[2 * t + 1];
    int bb = gi / N_, iw = gi - bb * N_;
    bool ma = false, mb = false;
#pragma unroll
    for (int q = 0; q < K_; ++q) {
      ma = ma || (idx[ga * K_ + q] == iw);
      mb = mb || (idx[gb * K_ + q] == iw);
    }
    if (ma && mb) continue;           // graphs identical: flip has zero effect
    int rows3[3] = {gi, ga, gb};
    int nn3[3];
    for (int s3 = 0; s3 < 3; ++s3) {
      int r = rows3[s3];
      int cc = cnti[r], oo = offi[r];
      int nn = 6 + cc; nn3[s3] = nn;
      for (int e = f; e < DCAP; e += 128) {
        int li = -1; float lw = 0.f;
        if (e < 6)      { li = L6[(size_t)r * 6 + e]; lw = W6[(size_t)r * 6 + e]; }
        else if (e < nn){ li = pooli[oo + e - 6];     lw = poolw[oo + e - 6]; }
        Ls[s3][e] = li; Wsh[s3][e] = lw;
      }
    }
    for (int s3 = 0; s3 < 3; ++s3) {
      int r = rows3[s3];
      float s1 = sumP[(size_t)r * 128 + f], d1 = degv[r];
      float ds = 0.f, dd = 0.f;
      if (s3 == 0) {
        if (!ma) { ds -= P[(size_t)ga * 128 + f]; dd -= 1.f; }
        if (!mb) { ds += P[(size_t)gb * 128 + f]; dd += 1.f; }
      } else if (s3 == 1) {
        if (!ma) { ds -= P[(size_t)gi * 128 + f]; dd -= 1.f; }
      } else {
        if (!mb) { ds += P[(size_t)gi * 128 + f]; dd += 1.f; }
      }
      float base = b1[f] + Qb[(size_t)r * 128 + f];
      float h0 = fmaxf(s1 / d1 + base, 0.f);
      float h1v = fmaxf((s1 + ds) / (d1 + dd) + base, 0.f);
      H[s3][0][f] = h0;
      H[s3][1][f] = h1v;
      dH[s3][f] = h1v - h0;
    }
    __syncthreads();
    {
      float u0 = 0.f, u1 = 0.f, u2 = 0.f;
      for (int f2 = 0; f2 < 128; ++f2) {
        float wv = W2l[f * 128 + f2];
        u0 += dH[0][f2] * wv;
        u1 += dH[1][f2] * wv;
        u2 += dH[2][f2] * wv;
      }
      U[0][f] = u0; U[1][f] = u1; U[2][f] = u2;
    }
    __syncthreads();
    // mU[s] = max_ff |U[s][ff]| (scratch: red/V1/V2 — rewritten below anyway)
    red[f] = fabsf(U[0][f]);
    V1[f]  = fabsf(U[1][f]);
    V2[f]  = fabsf(U[2][f]);
    __syncthreads();
    for (int o = 64; o > 0; o >>= 1) {
      if (f < o) {
        red[f] = fmaxf(red[f], red[f + o]);
        V1[f]  = fmaxf(V1[f],  V1[f + o]);
        V2[f]  = fmaxf(V2[f],  V2[f + o]);
      }
      __syncthreads();
    }
    if (f == 0) { mU[0] = red[0]; mU[1] = V1[0]; mU[2] = V2[0]; }
    __syncthreads();
    float dmax = 0.f;
    for (int which = 0; which < 3; ++which) {
      float v1 = 0.f, v2 = 0.f;
      float d1r = degv[rows3[which]], d2r = d1r;
      int nnw = nn3[which];
      for (int e2 = 0; e2 < nnw; ++e2) {
        float w = Wsh[which][e2];
        if (w == 0.f) continue;
        int s = Ls[which][e2];
        float hv1, hv2;
        if (s == gi)      { hv1 = H[0][0][f]; hv2 = H[0][1][f]; }
        else if (s == ga) { hv1 = H[1][0][f]; hv2 = H[1][1][f]; }
        else if (s == gb) { hv1 = H[2][0][f]; hv2 = H[2][1][f]; }
        else {
          float hh = bf2f(h1b[(size_t)s * 256 + f]) + bf2f(h1b[(size_t)s * 256 + 128 + f]);
          hv1 = hh; hv2 = hh;
        }
        bool inG2 = true;
        if (which == 0 && s == ga && !ma) inG2 = false;  // i loses a
        if (which == 1 && s == gi && !ma) inG2 = false;  // a loses i
        v1 += w * hv1;
        if (inG2) v2 += w * hv2; else d2r -= w;
      }
      if (which == 0 && !mb) { v2 += H[2][1][f]; d2r += 1.f; }  // i gains b
      if (which == 2 && !mb) { v2 += H[0][1][f]; d2r += 1.f; }  // b gains i
      V1[f] = v1; V2[f] = v2;
      __syncthreads();
      float a1 = 0.f, a2 = 0.f, ow = 0.f;
      for (int f2 = 0; f2 < 128; ++f2) {
        float wl = W2l[f * 128 + f2];
        a1 += V1[f2] * wl;
        a2 += V2[f2] * wl;
        ow += dH[which][f2] * W2r[f * 128 + f2];
      }
      dmax = fmaxf(dmax, fabsf(a2 / d2r - a1 / d1r + ow));
      __syncthreads();
    }
    for (int li = 0; li < 3; ++li) {
      for (int e = f; e < nn3[li]; e += 128) {
        float w = Wsh[li][e];
        if (w == 0.f) continue;
        int r = Ls[li][e];
        if (r == gi || r == ga || r == gb) continue;
        bool dup = false;
        for (int lj = 0; lj < li && !dup; ++lj)
          for (int e2 = 0; e2 < nn3[lj]; ++e2)
            if (Ls[lj][e2] == r && Wsh[lj][e2] != 0.f) { dup = true; break; }
        if (dup) continue;
        float wi = 0.f, wa = 0.f, wb = 0.f;
        if (li == 0) wi = w; else if (li == 1) wa = w; else wb = w;
        int nz = 1;
        for (int lj = li + 1; lj < 3; ++lj)
          for (int e2 = 0; e2 < nn3[lj]; ++e2)
            if (Ls[lj][e2] == r && Wsh[lj][e2] != 0.f) {
              if (lj == 1) { if (wa == 0.f) ++nz; wa = Wsh[lj][e2]; }
              else         { if (wb == 0.f) ++nz; wb = Wsh[lj][e2]; }
            }
        float lm;
        if (nz == 1) {
          lm = (li == 0) ? wi * mU[0] : (li == 1) ? wa * mU[1] : wb * mU[2];
        } else {
          lm = 0.f;
          for (int ff = 0; ff < 128; ++ff)
            lm = fmaxf(lm, fabsf(wi * U[0][ff] + wa * U[1][ff] + wb * U[2][ff]));
        }
        dmax = fmaxf(dmax, lm / degv[r]);
      }
    }
    red[f] = dmax;
    __syncthreads();
    for (int o = 64; o > 0; o >>= 1) {
      if (f < o) red[f] = fmaxf(red[f], red[f + o]);
      __syncthreads();
    }
    if (f == 0 && red[0] < DELTA_MAX) {
      c6[gi] = gb - bb * N_;
      int p = atomicAdd(dcnt, 3);
      dlist[p] = gi; dlist[p + 1] = ga; dlist[p + 2] = gb;
    }
    __syncthreads();
  }
}

// ---------------------------------------------------------------------------
// K3: dual near-exact GEMM, two-phase W staging (65 KB -> 2 blocks/CU).
#define WSTR 130
__global__ __launch_bounds__(256) void k_gemm(const unsigned short* __restrict__ A,
                                              const unsigned short* __restrict__ Whl,
                                              const unsigned short* __restrict__ Whr,
                                              const unsigned short* __restrict__ Wll,
                                              const unsigned short* __restrict__ Wlr,
                                              float* __restrict__ P, float* __restrict__ Q) {
  __shared__ unsigned short W[2 * 128 * WSTR];  // 65 KiB: [hi(128) | lo(128)]
  int tid = threadIdx.x, wave = tid >> 6, lane = tid & 63;

  size_t row = (size_t)blockIdx.x * 64 + wave * 16 + (lane & 15);
  bf16x8 af[8];
#pragma unroll
  for (int s = 0; s < 2; ++s)
#pragma unroll
    for (int kc = 0; kc < 4; ++kc)
      af[s * 4 + kc] = *(const bf16x8*)&A[row * 256 + s * 128 + kc * 32 + (lane >> 4) * 8];

  size_t orow0 = (size_t)blockIdx.x * 64 + wave * 16 + (lane >> 4) * 4;
#pragma unroll
  for (int w = 0; w < 2; ++w) {
    // stage this phase's hi/lo weight pair (1 row per thread, 256 rows)
    {
      int mat = tid >> 7, nrow = tid & 127;
      const unsigned short* src =
          (mat == 0) ? ((w == 0) ? Whl : Whr) + nrow * 128
                     : ((w == 0) ? Wll : Wlr) + nrow * 128;
      unsigned short* dst = &W[(size_t)tid * WSTR];
      if (w) __syncthreads();         // all waves done reading phase-0 W
#pragma unroll
      for (int p = 0; p < 16; ++p) *(bf16x8*)(dst + p * 8) = *(const bf16x8*)(src + p * 8);
    }
    __syncthreads();

    float* O = w ? Q : P;
#pragma unroll
    for (int ct = 0; ct < 8; ++ct) {
      f32x4 acc = {0.f, 0.f, 0.f, 0.f};
      int n = ct * 16 + (lane & 15);
      const unsigned short* bh = &W[(size_t)n * WSTR];
      const unsigned short* bl = &W[(size_t)(128 + n) * WSTR];
#pragma unroll
      for (int kc = 0; kc < 4; ++kc) {
        bf16x8 fh = *(const bf16x8*)(bh + kc * 32 + (lane >> 4) * 8);
        bf16x8 fl_ = *(const bf16x8*)(bl + kc * 32 + (lane >> 4) * 8);
        acc = __builtin_amdgcn_mfma_f32_16x16x32_bf16(af[kc], fh, acc, 0, 0, 0);
        acc = __builtin_amdgcn_mfma_f32_16x16x32_bf16(af[4 + kc], fh, acc, 0, 0, 0);
        acc = __builtin_amdgcn_mfma_f32_16x16x32_bf16(af[kc], fl_, acc, 0, 0, 0);
      }
#pragma unroll
      for (int r = 0; r < 4; ++r)
        O[(orow0 + r) * 128 + ct * 16 + (lane & 15)] = acc[r];
    }
  }
}

// K3b: dirty-row GEMM — identical arithmetic, rows indirected via dlist.
__global__ __launch_bounds__(256) void k_gemm_d(const unsigned short* __restrict__ A,
                                                const unsigned short* __restrict__ Whl,
                                                const unsigned short* __restrict__ Whr,
                                                const unsigned short* __restrict__ Wll,
                                                const unsigned short* __restrict__ Wlr,
                                                float* __restrict__ P, float* __restrict__ Q,
                                                const int* __restrict__ dcnt,
                                                const int* __restrict__ dlist) {
  int dn = *dcnt;
  if (blockIdx.x * 64 >= dn) return;
  __shared__ unsigned short W[4 * 128 * WSTR];
  int tid = threadIdx.x, wave = tid >> 6, lane = tid & 63;
#pragma unroll
  for (int q = 0; q < 2; ++q) {
    int ridx = tid * 2 + q;
    int mat = ridx >> 7, n = ridx & 127;
    const unsigned short* src =
        ((mat == 0) ? Whl : (mat == 1) ? Whr : (mat == 2) ? Wll : Wlr) + n * 128;
    unsigned short* dst = &W[(size_t)ridx * WSTR];
#pragma unroll
    for (int p = 0; p < 16; ++p) *(bf16x8*)(dst + p * 8) = *(const bf16x8*)(src + p * 8);
  }
  __syncthreads();

  for (int tb = blockIdx.x * 64; tb < dn; tb += gridDim.x * 64) {
    size_t row = (size_t)dlist[min(tb + wave * 16 + (lane & 15), dn - 1)];
    bf16x8 af[8];
#pragma unroll
    for (int s = 0; s < 2; ++s)
#pragma unroll
      for (int kc = 0; kc < 4; ++kc)
        af[s * 4 + kc] = *(const bf16x8*)&A[row * 256 + s * 128 + kc * 32 + (lane >> 4) * 8];

    int lo0 = tb + wave * 16 + (lane >> 4) * 4;
#pragma unroll
    for (int w = 0; w < 2; ++w) {
      float* O = w ? Q : P;
#pragma unroll
      for (int ct = 0; ct < 8; ++ct) {
        f32x4 acc = {0.f, 0.f, 0.f, 0.f};
        int n = ct * 16 + (lane & 15);
        const unsigned short* bh = &W[(size_t)(w * 128 + n) * WSTR];
        const unsigned short* bl = &W[(size_t)((2 + w) * 128 + n) * WSTR];
#pragma unroll
        for (int kc = 0; kc < 4; ++kc) {
          bf16x8 fh = *(const bf16x8*)(bh + kc * 32 + (lane >> 4) * 8);
          bf16x8 fl_ = *(const bf16x8*)(bl + kc * 32 + (lane >> 4) * 8);
          acc = __builtin_amdgcn_mfma_f32_16x16x32_bf16(af[kc], fh, acc, 0, 0, 0);
          acc = __builtin_amdgcn_mfma_f32_16x16x32_bf16(af[4 + kc], fh, acc, 0, 0, 0);
          acc = __builtin_amdgcn_mfma_f32_16x16x32_bf16(af[kc], fl_, acc, 0, 0, 0);
        }
#pragma unroll
        for (int r = 0; r < 4; ++r) {
          size_t orow = (size_t)dlist[min(lo0 + r, dn - 1)];
          O[orow * 128 + ct * 16 + (lane & 15)] = acc[r];
        }
      }
    }
  }
}

// ---------------------------------------------------------------------------
// K4: weighted aggregation over base-6 + CSR in-edges (canonical order).
// XCD-aware block swizzle (T1) for L2 batch-window locality.
__global__ __launch_bounds__(256) void k_aggr(const float* __restrict__ P,
                                              const float* __restrict__ Q,
                                              const int* __restrict__ L6,
                                              const float* __restrict__ W6,
                                              const int* __restrict__ pooli,
                                              const float* __restrict__ poolw,
                                              const int* __restrict__ offi,
                                              const int* __restrict__ cnti,
                                              const float* __restrict__ bias,
                                              float* __restrict__ outf,
                                              unsigned short* __restrict__ outb,
                                              float* __restrict__ sumP,
                                              float* __restrict__ degv,
                                              int relu) {
  int bid = blockIdx.x;
  int chunk = (bid & 7) * (gridDim.x >> 3) + (bid >> 3);   // grid % 8 == 0
  int r = chunk * 8 + (threadIdx.x >> 5);
  int l4 = threadIdx.x & 31;                // features 4*l4 .. 4*l4+3
  int m = cnti[r], o = offi[r];
  float4 acc = {0.f, 0.f, 0.f, 0.f};
  float deg = 0.f;
#pragma unroll
  for (int k = 0; k < 6; ++k) {
    float ww = W6[(size_t)r * 6 + k];
    float4 p4 = *(const float4*)&P[(size_t)L6[(size_t)r * 6 + k] * 128 + l4 * 4];
    acc.x += ww * p4.x; acc.y += ww * p4.y;
    acc.z += ww * p4.z; acc.w += ww * p4.w;
    deg += ww;
  }
  for (int q = 0; q < m; ++q) {
    float ww = poolw[o + q];
    float4 p4 = *(const float4*)&P[(size_t)pooli[o + q] * 128 + l4 * 4];
    acc.x += ww * p4.x; acc.y += ww * p4.y;
    acc.z += ww * p4.z; acc.w += ww * p4.w;
    deg += ww;
  }
  if (sumP) {
    *(float4*)&sumP[(size_t)r * 128 + l4 * 4] = acc;
    if (l4 == 0) degv[r] = deg;
  }
  float4 b4 = *(const float4*)&bias[l4 * 4];
  float4 q4 = *(const float4*)&Q[(size_t)r * 128 + l4 * 4];
  float4 v;
  v.x = acc.x / deg + b4.x + q4.x;
  v.y = acc.y / deg + b4.y + q4.y;
  v.z = acc.z / deg + b4.z + q4.z;
  v.w = acc.w / deg + b4.w + q4.w;
  if (relu) {
    v.x = fmaxf(v.x, 0.f); v.y = fmaxf(v.y, 0.f);
    v.z = fmaxf(v.z, 0.f); v.w = fmaxf(v.w, 0.f);
  }
  if (outf) {
    *(float4*)&outf[(size_t)r * 128 + l4 * 4] = v;
  } else {
    ushort4 hi, lo;
    hi.x = f2bf(v.x); hi.y = f2bf(v.y); hi.z = f2bf(v.z); hi.w = f2bf(v.w);
    lo.x = f2bf(v.x - bf2f(hi.x)); lo.y = f2bf(v.y - bf2f(hi.y));
    lo.z = f2bf(v.z - bf2f(hi.z)); lo.w = f2bf(v.w - bf2f(hi.w));
    *(ushort4*)&outb[(size_t)r * 256 + l4 * 4] = hi;
    *(ushort4*)&outb[(size_t)r * 256 + 128 + l4 * 4] = lo;
  }
}

// K4b: dirty-row h1 recompute (relu=1, bf16 hi/lo out) over hedged lists.
__global__ __launch_bounds__(256) void k_aggr_d(const float* __restrict__ P,
                                                const float* __restrict__ Q,
                                                const int* __restrict__ L6,
                                                const float* __restrict__ W6,
                                                const int* __restrict__ pooli,
                                                const float* __restrict__ poolw,
                                                const int* __restrict__ offi,
                                                const int* __restrict__ cnti,
                                                const float* __restrict__ bias,
                                                unsigned short* __restrict__ outb,
                                                const int* __restrict__ dcnt,
                                                const int* __restrict__ dlist) {
  int dn = *dcnt;
  int l4 = threadIdx.x & 31;
  for (int di = blockIdx.x * 8 + (threadIdx.x >> 5); di < dn; di += gridDim.x * 8) {
    int r = dlist[di];
    int m = cnti[r], o = offi[r];
    float4 acc = {0.f, 0.f, 0.f, 0.f};
    float deg = 0.f;
#pragma unroll
    for (int k = 0; k < 6; ++k) {
      float ww = W6[(size_t)r * 6 + k];
      float4 p4 = *(const float4*)&P[(size_t)L6[(size_t)r * 6 + k] * 128 + l4 * 4];
      acc.x += ww * p4.x; acc.y += ww * p4.y;
      acc.z += ww * p4.z; acc.w += ww * p4.w;
      deg += ww;
    }
    for (int q = 0; q < m; ++q) {
      float ww = poolw[o + q];
      float4 p4 = *(const float4*)&P[(size_t)pooli[o + q] * 128 + l4 * 4];
      acc.x += ww * p4.x; acc.y += ww * p4.y;
      acc.z += ww * p4.z; acc.w += ww * p4.w;
      deg += ww;
    }
    float4 b4 = *(const float4*)&bias[l4 * 4];
    float4 q4 = *(const float4*)&Q[(size_t)r * 128 + l4 * 4];
    float4 v;
    v.x = fmaxf(acc.x / deg + b4.x + q4.x, 0.f);
    v.y = fmaxf(acc.y / deg + b4.y + q4.y, 0.f);
    v.z = fmaxf(acc.z / deg + b4.z + q4.z, 0.f);
    v.w = fmaxf(acc.w / deg + b4.w + q4.w, 0.f);
    ushort4 hi, lo;
    hi.x = f2bf(v.x); hi.y = f2bf(v.y); hi.z = f2bf(v.z); hi.w = f2bf(v.w);
    lo.x = f2bf(v.x - bf2f(hi.x)); lo.y = f2bf(v.y - bf2f(hi.y));
    lo.z = f2bf(v.z - bf2f(hi.z)); lo.w = f2bf(v.w - bf2f(hi.w));
    *(ushort4*)&outb[(size_t)r * 256 + l4 * 4] = hi;
    *(ushort4*)&outb[(size_t)r * 256 + 128 + l4 * 4] = lo;
  }
}

// ---------------------------------------------------------------------------
extern "C" void kernel_launch(void* const* d_in, const int* in_sizes, int n_in,
                              void* d_out, int out_size, void* d_ws, size_t ws_size,
                              hipStream_t stream) {
  const float* x   = (const float*)d_in[0];
  const float* W1l = (const float*)d_in[1];
  const float* b1l = (const float*)d_in[2];
  const float* W1r = (const float*)d_in[3];
  const float* W2l = (const float*)d_in[4];
  const float* b2l = (const float*)d_in[5];
  const float* W2r = (const float*)d_in[6];
  float* out = (float*)d_out;

  // Workspace (~151 MB). P2 aliases Y (dead after layer-1 GEMM);
  // Q2 aliases sumP (dead after k_delta).
  char* w = (char*)d_ws;
  unsigned short* Y    = (unsigned short*)w; w += (size_t)ROWS * 256 * 2;
  float*          sq   = (float*)w;          w += (size_t)ROWS * 4;
  unsigned short* Wh   = (unsigned short*)w; w += (size_t)4 * 16384 * 2;
  unsigned short* Wlo  = (unsigned short*)w; w += (size_t)4 * 16384 * 2;
  int*            idx  = (int*)w;            w += (size_t)ROWS * K_ * 4;
  int*            L6   = (int*)w;            w += (size_t)ROWS * 6 * 4;
  float*          W6   = (float*)w;          w += (size_t)ROWS * 6 * 4;
  int*            pooli= (int*)w;            w += (size_t)B_ * POOLCAP * 4;
  float*          poolw= (float*)w;          w += (size_t)B_ * POOLCAP * 4;
  int*            offi = (int*)w;            w += (size_t)ROWS * 4;
  int*            cnti = (int*)w;            w += (size_t)ROWS * 4;
  int*            flags = (int*)w;           w += 64;   // [0]=flagcnt [1]=hcnt [2]=dcnt
  int*            c6   = (int*)w;            w += (size_t)ROWS * 4;
  int*            dlist= (int*)w;            w += (size_t)3 * MAXFLAG * 4;
  int*            flagrows = (int*)w;        w += (size_t)MAXFLAG * 4;
  int*            hrows = (int*)w;           w += (size_t)MAXFLAG * 4;
  int*            hab  = (int*)w;            w += (size_t)MAXFLAG * 8;
  int*            candb = (int*)w;           w += (size_t)ROWS * 32 * 4;
  float*          halfdb = (float*)w;        w += (size_t)ROWS * 12 * 4;
  int*            halfjb = (int*)w;          w += (size_t)ROWS * 12 * 4;
  float*          P    = (float*)w;          w += (size_t)ROWS * 128 * 4;
  float*          Qb   = (float*)w;          w += (size_t)ROWS * 128 * 4;
  unsigned short* h1b  = (unsigned short*)w; w += (size_t)ROWS * 256 * 2;
  float*          sumP = (float*)w;          w += (size_t)ROWS * 128 * 4;
  float*          degv = (float*)w;          w += (size_t)ROWS * 4;
  float* P2 = (float*)Y;      // layer-2 lin_l output (Y dead after gemm1)
  float* Q2 = sumP;           // layer-2 lin_r output (sumP dead after delta)
  (void)ws_size; (void)in_sizes; (void)n_in; (void)out_size;

  hipMemsetAsync(flags, 0, 64, stream);
  hipMemsetAsync(c6, 0xFF, (size_t)ROWS * 4, stream);          // c6 = -1
  k_prep_rows<<<ROWS / 4, 256, 0, stream>>>(x, Y, sq);
  k_prep_w<<<(4 * 16384) / 256, 256, 0, stream>>>(W1l, W1r, W2l, W2r, Wh, Wlo);
  k_knn<<<dim3(7, B_, 2), 256, 0, stream>>>(Y, sq, halfdb, halfjb);
  k_kmerge<<<ROWS / 256, 256, 0, stream>>>(halfdb, halfjb, idx, &flags[0],
                                           flagrows, candb);
  // layer-1 GEMM early: P/Qb are graph-independent, needed by k_delta.
  k_gemm<<<ROWS / 64, 256, 0, stream>>>(Y, Wh, Wh + 16384, Wlo, Wlo + 16384, P, Qb);
  k_refine<<<256, 256, 0, stream>>>(x, flagrows, &flags[0], candb, idx,
                                    &flags[1], hrows, hab);
  // pass 1: unhedged build + aggregation (records sumP/degv/h1 for k_delta)
  k_buildg<<<B_, 512, 0, stream>>>(idx, c6, L6, W6, pooli, poolw, offi, cnti);
  k_aggr<<<ROWS / 8, 256, 0, stream>>>(P, Qb, L6, W6, pooli, poolw, offi, cnti,
                                       b1l, nullptr, h1b, sumP, degv, 1);
  k_delta<<<512, 128, 0, stream>>>(P, Qb, b1l, h1b, sumP, degv, L6, W6, pooli,
                                   poolw, offi, cnti, idx, &flags[1], hrows, hab,
                                   W2l, W2r, c6, &flags[2], dlist);
  // pass 2 (surgical): rebuild lists; full layer-2 GEMM on pass-1 h1 (valid for
  // all non-dirty rows); then fix only dirty rows' h1 and P2/Q2; final aggr.
  k_buildg<<<B_, 512, 0, stream>>>(idx, c6, L6, W6, pooli, poolw, offi, cnti);
  k_gemm<<<ROWS / 64, 256, 0, stream>>>(h1b, Wh + 2 * 16384, Wh + 3 * 16384,
                                        Wlo + 2 * 16384, Wlo + 3 * 16384, P2, Q2);
  k_aggr_d<<<64, 256, 0, stream>>>(P, Qb, L6, W6, pooli, poolw, offi, cnti,
                                   b1l, h1b, &flags[2], dlist);
  k_gemm_d<<<32, 256, 0, stream>>>(h1b, Wh + 2 * 16384, Wh + 3 * 16384,
                                   Wlo + 2 * 16384, Wlo + 3 * 16384, P2, Q2,
                                   &flags[2], dlist);
  k_aggr<<<ROWS / 8, 256, 0, stream>>>(P2, Q2, L6, W6, pooli, poolw, offi, cnti,
                                       b2l, out, nullptr, nullptr, nullptr, 0);
}